// Round 2
// baseline (125.314 us; speedup 1.0000x reference)
//
#include <hip/hip_runtime.h>
#include <hip/hip_bf16.h>

// out[b,k] = sum_{i,j} x[b,i] * W[k,i,j] * x[b,j]
// GEMM P (B x 160 XOR-classed pair-products) @ Q (160 x 16),
// 5 x mfma_f32_16x16x32_bf16 per 16-row tile.
//
// R7: REVERT to the harness-verified R5 dataflow (A = product-frags,
// B = Q-frags, LDS-transpose epilogue — bit-identical values to the
// absmax-0.0625 kernel). R6's operand swap failed correctness despite a
// layout-symmetry argument saying it should be exact — do NOT retry the
// swap without isolating it. This round changes ONLY schedule/occupancy:
//   1) __launch_bounds__(256,4): reg cap 64 -> 128. R5's (256,8) squeeze
//      (VGPR_Count=32, acc juggled through AGPRs) bought nothing: measured
//      occupancy was 47% anyway, and it forced ONE load in flight/wave ->
//      2.44 TB/s, latency-bound (MfmaUtil 4.7%, VALU 42%, no pipe hot).
//   2) 2-tile unroll + distance-2 register prefetch: 2-4 independent
//      global_load_dwordx4 in flight per wave; ~900cy HBM latency hides
//      under the shfl/VALU/MFMA/DS chain of the current pair.
//
// XOR class algebra unchanged: K-slot k = 32s + 8q + j holds, at lane
// quad q, x[alpha_c^4q]*x[beta_c^4q], c = 8s+j; coverage verified by
// orbit enumeration (120 off-diag pairs weight 1, 16 diagonals once).
//
// Memory structure:
//   load : ONE global_load_dwordx4 per tile (lane (n,q) loads chunk q of
//          row n). Chunks q^1, q^2 via __shfl_xor(.,16)/(.,32).
//   store: ONE global_store_dwordx4 per tile after a wave-internal LDS
//          transpose (16 rows x 20-dword padded stride; same-wave DS ops
//          are ordered, so no barrier needed).

typedef __attribute__((ext_vector_type(8)))  short  short8;
typedef __attribute__((ext_vector_type(8)))  __bf16 bf16x8;
typedef __attribute__((ext_vector_type(4)))  float  floatx4;

#define DEV static __device__ __forceinline__

// ---- XOR class table ----
constexpr int cA(int c) {            // alpha
    if (c < 24) { const int dIdx = c >> 1, v = c & 1;
        const int hi = dIdx / 3, lo = dIdx % 3 + 1;
        const int base = (hi == 3) ? 1 : 0;
        const int l = v ? ((lo == 1) ? 2 : 1) : 0;
        return base * 4 + l; }
    if (c < 36) { const int g = c - 24, hi = g / 4 + 1, l = g & 3;
        const int base = (hi == 3) ? 1 : 0;
        return base * 4 + l; }
    return c - 36;
}
constexpr int cDd(int c) {           // d = alpha ^ beta
    if (c < 24) { const int dIdx = c >> 1;
        return (dIdx / 3) * 4 + (dIdx % 3 + 1); }
    if (c < 36) { return ((c - 24) / 4 + 1) * 4; }
    return 0;
}
constexpr int   cB(int c) { return cA(c) ^ cDd(c); }
constexpr float cW(int c) { return (c >= 24 && c < 36) ? 0.5f : 1.0f; }

template <int C>
DEV float pval(const float* xv) {    // xv indexed directly by value id (<=11)
    return xv[cA(C)] * xv[cB(C)];
}

template <int S>   // frag S covers classes c = 8S .. 8S+7
DEV short8 make_afrag(const float* xv) {
    union { short8 s; __hip_bfloat162 h[4]; } u;
    u.h[0] = __float22bfloat162_rn(make_float2(pval<8 * S + 0>(xv), pval<8 * S + 1>(xv)));
    u.h[1] = __float22bfloat162_rn(make_float2(pval<8 * S + 2>(xv), pval<8 * S + 3>(xv)));
    u.h[2] = __float22bfloat162_rn(make_float2(pval<8 * S + 4>(xv), pval<8 * S + 5>(xv)));
    u.h[3] = __float22bfloat162_rn(make_float2(pval<8 * S + 6>(xv), pval<8 * S + 7>(xv)));
    return u.s;
}

DEV floatx4 mfma_bf16(short8 a, short8 b, floatx4 c) {
    return __builtin_amdgcn_mfma_f32_16x16x32_bf16(
        __builtin_bit_cast(bf16x8, a), __builtin_bit_cast(bf16x8, b), c, 0, 0, 0);
}

// ---- Q element for flat slot e = n*160 + k,  k = 32s + 8q + j ----
DEV float q_elem(const float* __restrict__ W, int e) {
    const int n = e / 160;
    const int k = e - n * 160;
    const int s = k >> 5, q = (k >> 3) & 3, j = k & 7;
    const int c = 8 * s + j;
    const int I = cA(c) ^ (q << 2);
    const int J = cB(c) ^ (q << 2);
    return (I == J) ? W[n * 256 + I * 16 + I]
                    : cW(c) * (W[n * 256 + I * 16 + J] + W[n * 256 + J * 16 + I]);
}

__global__ __launch_bounds__(256, 4)
void bilinear16_kernel(const float* __restrict__ x, const float* __restrict__ W,
                       float* __restrict__ out, int ntiles) {
    __shared__ __align__(16) short Qt[16][160];   // 5120 B
    __shared__ __align__(16) float Tb[4][320];    // 4 waves x (16 rows x 20 dw) = 5120 B

    const int tid = threadIdx.x;
    for (int e = tid; e < 16 * 160; e += 256) {
        __hip_bfloat16 h = __float2bfloat16(q_elem(W, e));
        Qt[0][e] = *reinterpret_cast<short*>(&h);
    }
    __syncthreads();

    const int lane = tid & 63;
    const int n    = lane & 15;   // MFMA A-row / C col (fixed by HW layout)
    const int q    = lane >> 4;   // MFMA k-group quad
    float* const tb = Tb[tid >> 6];

    // B-frags (20 VGPRs), resident across the loop.
    const short8 b0 = *reinterpret_cast<const short8*>(&Qt[n][0 * 32 + q * 8]);
    const short8 b1 = *reinterpret_cast<const short8*>(&Qt[n][1 * 32 + q * 8]);
    const short8 b2 = *reinterpret_cast<const short8*>(&Qt[n][2 * 32 + q * 8]);
    const short8 b3 = *reinterpret_cast<const short8*>(&Qt[n][3 * 32 + q * 8]);
    const short8 b4 = *reinterpret_cast<const short8*>(&Qt[n][4 * 32 + q * 8]);

    const int waveId = blockIdx.x * 4 + (tid >> 6);
    const int nwaves = gridDim.x * 4;
    const int off    = n * 16 + q * 4;     // float offset within a tile
    const int stride = nwaves * 2;

    // Verified R5 tile body: compute + LDS transpose + coalesced store.
    auto tile = [&](const float4 own, float* obase) {
        float4 s1, s2;                 // chunk q^1 from lane^16, chunk q^2 from lane^32
        s1.x = __shfl_xor(own.x, 16); s1.y = __shfl_xor(own.y, 16);
        s1.z = __shfl_xor(own.z, 16); s1.w = __shfl_xor(own.w, 16);
        s2.x = __shfl_xor(own.x, 32); s2.y = __shfl_xor(own.y, 32);
        s2.z = __shfl_xor(own.z, 32); s2.w = __shfl_xor(own.w, 32);
        const float xv[12] = {own.x, own.y, own.z, own.w,
                              s1.x,  s1.y,  s1.z,  s1.w,
                              s2.x,  s2.y,  s2.z,  s2.w};
        floatx4 acc = {0.f, 0.f, 0.f, 0.f};
        acc = mfma_bf16(make_afrag<0>(xv), b0, acc);
        acc = mfma_bf16(make_afrag<1>(xv), b1, acc);
        acc = mfma_bf16(make_afrag<2>(xv), b2, acc);
        acc = mfma_bf16(make_afrag<3>(xv), b3, acc);
        acc = mfma_bf16(make_afrag<4>(xv), b4, acc);

        // C/D layout: col = lane&15, row = q*4 + reg  [m89-verified].
        // Wave-internal LDS transpose -> lane-linear float4 store.
        tb[(q * 4 + 0) * 20 + n] = acc[0];
        tb[(q * 4 + 1) * 20 + n] = acc[1];
        tb[(q * 4 + 2) * 20 + n] = acc[2];
        tb[(q * 4 + 3) * 20 + n] = acc[3];
        const float4 o = *reinterpret_cast<const float4*>(
            &tb[(lane >> 2) * 20 + (lane & 3) * 4]);
        *reinterpret_cast<float4*>(obase + lane * 4) = o;
    };

    const int t0 = waveId * 2;
    if (t0 + 1 >= ntiles) return;

    // Distance-2 prefetch pipeline: current pair (c0,c1), next pair (n0,n1).
    auto ldp = [&](int tt) -> float4 {
        return *reinterpret_cast<const float4*>(x + (size_t)tt * 256 + off);
    };
    int t = t0;
    float4 c0 = ldp(t), c1 = ldp(t + 1);
    int t1 = t + stride; if (t1 + 1 >= ntiles) t1 = t0;   // clamp (safe reload)
    float4 n0 = ldp(t1), n1 = ldp(t1 + 1);

    for (; t < ntiles; t += stride) {
        int tf = t + 2 * stride;
        if (tf + 1 >= ntiles) tf = t0;                    // clamp (safe reload)
        const float4 f0 = ldp(tf);
        const float4 f1 = ldp(tf + 1);

        tile(c0, out + (size_t)t * 256);
        tile(c1, out + (size_t)(t + 1) * 256);

        c0 = n0; c1 = n1;
        n0 = f0; n1 = f1;
    }
}

extern "C" void kernel_launch(void* const* d_in, const int* in_sizes, int n_in,
                              void* d_out, int out_size, void* d_ws, size_t ws_size,
                              hipStream_t stream) {
    const float* x = (const float*)d_in[0];
    const float* W = (const float*)d_in[1];
    float* out = (float*)d_out;
    const int Bn = in_sizes[0] / 16;   // 1048576
    const int ntiles = Bn >> 4;        // 65536
    // 2048 blocks x 4 waves = 8192 waves; 8 tiles/wave = 4 pair-iterations.
    bilinear16_kernel<<<2048, 256, 0, stream>>>(x, W, out, ntiles);
}